// Round 1
// 326.409 us; speedup vs baseline: 1.4749x; 1.4749x over previous
//
#include <hip/hip_runtime.h>

// ---------------------------------------------------------------------------
// ROUND 8: algebraic collapse. The circuit unitary U is batch-invariant and
// the encoded initial state (RX(x0)@w0, RY(x1)@w1)|0..0> spans only the
// 4-dim subspace of columns {0,1024,2048,3072}. With C = U[:,cols] (4096x4),
// v = D a, D = diag(1,1,-i,-i), a = (c0c1,c0s1,s0c1,s0s1) real:
//   out = v^H H v + hb,   H = sum_r K(r) C_r^H C_r,
//   K(r) = sum_w hw[w] * (1 - 2*bit_{11-w}(r))
// which for real a reduces to a real symmetric 4x4 quadratic form G
// (10 floats, batch-independent). So:
//   kernel 1: 96 fp32 gate records (batch-shared)          [~2 us]
//   kernel 2: 1 block x 256 thr = 4 waves, one fp32 column sim per wave
//             (verified deferred-gray lane bookkeeping from the fp16 kernel,
//              ALL 8 CNOT layers applied physically now), stage columns to
//             LDS in 4 passes of 1024 logical indices (33 KB static, padded
//             stride 65 to break bank conflicts), reduce to G    [~40-70 us]
//   kernel 3: 8192 threads, out[i] = a^T G a + hb          [~4 us]
// fp32 state = 128 VGPRs + 32 chunk temps; __launch_bounds__(256,1) gives a
// 512-reg budget so no AGPR shadowing / spill.
// Rot(phi,th,om) = [[(A,-B),(-C,-D)],[(C,-D),(A,B)]], A=ca*ch B=sa*ch
// C=cb*sh D=sb*sh.  Flat y = (lane<<6)|reg; wire w <-> flat bit 11-w.
// CNOT chain == new[d] = old[d ^ (d>>1)]: lane part deferred via (p, Minv),
// reg part = cond ^32 on parity(p_old) + fixed gray6 relabel (in-place
// cycle decomposition -> no 128-reg copy spike).
// ---------------------------------------------------------------------------

struct Gate32 { float a, b, c, d; };

__device__ __forceinline__ float bpermf(int addr4, float v) {
    return __int_as_float(__builtin_amdgcn_ds_bpermute(addr4, __float_as_int(v)));
}
__device__ __forceinline__ int ginv6(int y) {
    return (y ^ (y >> 1) ^ (y >> 2) ^ (y >> 3) ^ (y >> 4) ^ (y >> 5)) & 63;
}

// ---- kernel 1: fp32 gate-coefficient table (96 gates, batch-shared) -------
__global__ void coeff_kernel(const float* __restrict__ wts, Gate32* __restrict__ tbl) {
    const int g = threadIdx.x;
    if (g >= 96) return;
    const int l = g / 12, w = g % 12;
    const float* lw = wts + l*36 + w*3;
    const float phi = lw[0], th = lw[1], om = lw[2];
    float ch, sh, ca, sa, cb, sb;
    __sincosf(0.5f*th,       &sh, &ch);
    __sincosf(0.5f*(phi+om), &sa, &ca);
    __sincosf(0.5f*(phi-om), &sb, &cb);
    Gate32 r;
    r.a = ca*ch; r.b = sa*ch; r.c = cb*sh; r.d = sb*sh;
    tbl[g] = r;
}

// Gate on a logical lane bit; partner fetched from physical lane ^ Minv.
// self coeff (A, csi), partner coeff (cor, -D):
//   new_r = A*xr - csi*xi + cor*tr + D*ti
//   new_i = A*xi + csi*xr + cor*ti - D*tr
__device__ __forceinline__ void lane_gate32(float ar[64], float ai[64], int addr4,
                                            float A, float csi, float cor, float D) {
    constexpr int CH = 8;
    float tr[CH], ti[CH], pr[CH], pi[CH];
#pragma unroll
    for (int k = 0; k < CH; ++k) {
        tr[k] = bpermf(addr4, ar[k]);
        ti[k] = bpermf(addr4, ai[k]);
    }
#pragma unroll
    for (int base = 0; base < 64; base += CH) {
        if (base + CH < 64) {
#pragma unroll
            for (int k = 0; k < CH; ++k) {
                pr[k] = bpermf(addr4, ar[base+CH+k]);
                pi[k] = bpermf(addr4, ai[base+CH+k]);
            }
        }
#pragma unroll
        for (int k = 0; k < CH; ++k) {
            const int r = base + k;
            const float xr = ar[r], xi = ai[r];
            ar[r] = A*xr - csi*xi + cor*tr[k] + D*ti[k];
            ai[r] = A*xi + csi*xr + cor*ti[k] - D*tr[k];
        }
#pragma unroll
        for (int k = 0; k < CH; ++k) { tr[k] = pr[k]; ti[k] = pi[k]; }
    }
}

// Gate on reg bit BIT: pair (r0, r1=r0|1<<BIT) in-register.
template<int BIT>
__device__ __forceinline__ void reg_gate32(float ar[64], float ai[64], const Gate32 R) {
#pragma unroll
    for (int r0 = 0; r0 < 64; ++r0) {
        if (r0 & (1 << BIT)) continue;          // compile-time filtered
        const int r1 = r0 | (1 << BIT);
        const float x0r = ar[r0], x0i = ai[r0], x1r = ar[r1], x1i = ai[r1];
        ar[r0] = R.a*x0r + R.b*x0i - R.c*x1r + R.d*x1i;
        ai[r0] = R.a*x0i - R.b*x0r - R.c*x1i - R.d*x1r;
        ar[r1] = R.c*x0r + R.d*x0i + R.a*x1r - R.b*x1i;
        ai[r1] = R.c*x0i - R.d*x0r + R.a*x1i + R.b*x1r;
    }
}

// Fixed permutation new[r] = old[gray6(r)], applied in place via cycles of
// gamma(r) = r ^ (r>>1) on 6 bits (1 temp per cycle, no 128-reg copy spike).
#define CYC2(A,r0,r1) { float t=A[r0]; A[r0]=A[r1]; A[r1]=t; }
#define CYC4(A,r0,r1,r2,r3) { float t=A[r0]; A[r0]=A[r1]; A[r1]=A[r2]; A[r2]=A[r3]; A[r3]=t; }
#define CYC8(A,r0,r1,r2,r3,r4,r5,r6,r7) { float t=A[r0]; A[r0]=A[r1]; A[r1]=A[r2]; \
    A[r2]=A[r3]; A[r3]=A[r4]; A[r4]=A[r5]; A[r5]=A[r6]; A[r6]=A[r7]; A[r7]=t; }

__device__ __forceinline__ void gray_relabel(float a[64]) {
    CYC2(a, 2,3);
    CYC4(a, 4,6,5,7);
    CYC4(a, 8,12,10,15);
    CYC4(a, 9,13,11,14);
    CYC8(a, 16,24,20,30,17,25,21,31);
    CYC8(a, 18,27,22,29,19,26,23,28);
    CYC8(a, 32,48,40,60,34,51,42,63);
    CYC8(a, 33,49,41,61,35,50,43,62);
    CYC8(a, 36,54,45,59,38,53,47,56);
    CYC8(a, 37,55,44,58,39,52,46,57);
}

// CNOT reg-part: value_new[r] = value_old[gray6(r) ^ 32c], c = parity(p_old).
__device__ __forceinline__ void cnot32(float ar[64], float ai[64], int c) {
#pragma unroll
    for (int k = 0; k < 32; ++k) {
        float t = ar[k];
        ar[k]    = c ? ar[k+32] : ar[k];
        ar[k+32] = c ? t        : ar[k+32];
        t = ai[k];
        ai[k]    = c ? ai[k+32] : ai[k];
        ai[k+32] = c ? t        : ai[k+32];
    }
    gray_relabel(ar);
    gray_relabel(ai);
}

// ---- kernel 2: 4 column sims (1 wave each) + reduction to G ---------------
__global__ __launch_bounds__(256, 1)
void columns_kernel(const Gate32* __restrict__ recs,
                    const float* __restrict__ hw,
                    float* __restrict__ Gout) {
    const int tid  = threadIdx.x;
    const int lane = tid & 63;
    const int wid  = tid >> 6;                 // column j = b0*2+b1

    float ar[64], ai[64];
#pragma unroll
    for (int r = 0; r < 64; ++r) { ar[r] = 0.f; ai[r] = 0.f; }
    const int L0 = (wid >> 1) * 32 + (wid & 1) * 16;   // basis col lane
    if (lane == L0) ar[0] = 1.f;

    int p = lane;                               // logical lane of this lane's data
    int Minv[6] = {1, 2, 4, 8, 16, 32};

#pragma unroll 1
    for (int l = 0; l < 8; ++l) {
        const Gate32* lr = recs + l*12;
#pragma unroll
        for (int w = 0; w < 6; ++w) {           // wires 0..5 -> lane bits 5..0
            const Gate32 R = lr[w];             // wave-uniform -> s_load
            const int pb = 5 - w;
            const bool b = (p >> pb) & 1;
            const float csi = b ? R.b : -R.b;
            const float cor = b ? R.c : -R.c;
            lane_gate32(ar, ai, (lane ^ Minv[pb]) << 2, R.a, csi, cor, R.d);
        }
        reg_gate32<5>(ar, ai, lr[6]);           // wires 6..11 -> reg bits 5..0
        reg_gate32<4>(ar, ai, lr[7]);
        reg_gate32<3>(ar, ai, lr[8]);
        reg_gate32<2>(ar, ai, lr[9]);
        reg_gate32<1>(ar, ai, lr[10]);
        reg_gate32<0>(ar, ai, lr[11]);
        const int c = __popc(p) & 1;            // ALL 8 CNOT layers applied
        cnot32(ar, ai, c);
        p = ginv6(p);
#pragma unroll
        for (int pb = 5; pb >= 1; --pb) Minv[pb] ^= Minv[pb-1];
    }

    // ---- reduce: G_jk = sum_q K(q) * pair(C[q,j], C[q,k]) -----------------
    // logical flat idx of amp r in this lane = (p<<6)|r.  4 passes of 1024
    // logical idx (p in [16t,16t+16)); LDS row stride 65 float2 breaks the
    // 16-way bank conflict of stride 64.
    __shared__ float2 buf[4][16*65];            // 33,280 B
    __shared__ float  gsh[4][10];

    float hwv[12];
#pragma unroll
    for (int w = 0; w < 12; ++w) hwv[w] = hw[w];

    float g[10];
#pragma unroll
    for (int m = 0; m < 10; ++m) g[m] = 0.f;

    for (int t = 0; t < 4; ++t) {
        __syncthreads();                        // prev pass reads done
        if ((p >> 4) == t) {
            float2* dst = &buf[wid][(p & 15) * 65];
#pragma unroll
            for (int r = 0; r < 64; ++r) dst[r] = make_float2(ar[r], ai[r]);
        }
        __syncthreads();
#pragma unroll
        for (int m = 0; m < 4; ++m) {
            const int i1  = tid * 4 + m;        // 0..1023
            const int q   = (t << 10) | i1;     // logical flat idx
            const int off = (i1 >> 6) * 65 + (i1 & 63);
            const float2 c0 = buf[0][off];
            const float2 c1 = buf[1][off];
            const float2 c2 = buf[2][off];
            const float2 c3 = buf[3][off];
            float K = 0.f;                      // K(q) = sum_w hw[w]*sign_w(q)
#pragma unroll
            for (int w = 0; w < 12; ++w)
                K += ((q >> (11 - w)) & 1) ? -hwv[w] : hwv[w];
            // diag: |C_j|^2 ; (0,1),(2,3): Re(conj(Cj)Ck) ; cross: Im(conj(Cj)Ck)
            g[0] += K * (c0.x*c0.x + c0.y*c0.y);
            g[1] += K * (c1.x*c1.x + c1.y*c1.y);
            g[2] += K * (c2.x*c2.x + c2.y*c2.y);
            g[3] += K * (c3.x*c3.x + c3.y*c3.y);
            g[4] += K * (c0.x*c1.x + c0.y*c1.y);
            g[5] += K * (c2.x*c3.x + c2.y*c3.y);
            g[6] += K * (c0.x*c2.y - c0.y*c2.x);
            g[7] += K * (c0.x*c3.y - c0.y*c3.x);
            g[8] += K * (c1.x*c2.y - c1.y*c2.x);
            g[9] += K * (c1.x*c3.y - c1.y*c3.x);
        }
    }

    // block-reduce g[10]: wave butterfly then cross-wave via gsh
#pragma unroll
    for (int m = 0; m < 10; ++m) {
#pragma unroll
        for (int off = 1; off < 64; off <<= 1)
            g[m] += bpermf((lane ^ off) << 2, g[m]);
    }
    if (lane == 0) {
#pragma unroll
        for (int m = 0; m < 10; ++m) gsh[wid][m] = g[m];
    }
    __syncthreads();
    if (tid < 10) {
        const float s = gsh[0][tid] + gsh[1][tid] + gsh[2][tid] + gsh[3][tid];
        Gout[tid] = (tid < 4) ? s : 2.f * s;    // fold 2*Re factor for j<k
    }
}

// ---- kernel 3: per-sample quadratic form ----------------------------------
__global__ __launch_bounds__(256)
void apply_kernel(const float* __restrict__ sb,
                  const float* __restrict__ Gd,
                  const float* __restrict__ hb,
                  float* __restrict__ out, int B) {
    const int i = blockIdx.x * blockDim.x + threadIdx.x;
    if (i >= B) return;
    const float2 x = *reinterpret_cast<const float2*>(sb + i*8);
    float c0, s0, c1, s1;
    __sincosf(0.5f * x.x, &s0, &c0);
    __sincosf(0.5f * x.y, &s1, &c1);
    const float a0 = c0*c1, a1 = c0*s1, a2 = s0*c1, a3 = s0*s1;
    const float r = Gd[0]*a0*a0 + Gd[1]*a1*a1 + Gd[2]*a2*a2 + Gd[3]*a3*a3
                  + Gd[4]*(a0*a1) + Gd[5]*(a2*a3)
                  + Gd[6]*(a0*a2) + Gd[7]*(a0*a3)
                  + Gd[8]*(a1*a2) + Gd[9]*(a1*a3);
    out[i] = r + hb[0];
}

extern "C" void kernel_launch(void* const* d_in, const int* in_sizes, int n_in,
                              void* d_out, int out_size, void* d_ws, size_t ws_size,
                              hipStream_t stream) {
    const float* sb  = (const float*)d_in[0];
    const float* wts = (const float*)d_in[1];
    const float* hw  = (const float*)d_in[2];
    const float* hb  = (const float*)d_in[3];
    float* out = (float*)d_out;
    Gate32* tbl = (Gate32*)d_ws;                  // 96*16 B = 1536 B
    float*  G   = (float*)d_ws + 384;             // 10 floats @ offset 1536 B
    const int B = in_sizes[0] / 8;                // (B,8) state_batch
    coeff_kernel  <<<1, 128, 0, stream>>>(wts, tbl);
    columns_kernel<<<1, 256, 0, stream>>>(tbl, hw, G);
    apply_kernel  <<<(B + 255)/256, 256, 0, stream>>>(sb, G, hb, out, B);
}

// Round 3
// 111.773 us; speedup vs baseline: 4.3073x; 2.9203x over previous
//
#include <hip/hip_runtime.h>

// ---------------------------------------------------------------------------
// ROUND 10: round-9 structure (4 blocks x 512 thr, one unitary column per
// block, 8 complex/thread) with the RACE FIX: round 9 fused the gate-coeff
// table into sim_kernel but read gt[] (layer 0, wire 0) BEFORE any barrier --
// waves 2..7 raced ahead of the wave-0/1 table fill (absmax 35.6). One
// __syncthreads() after the fill fixes it; everything else is the verified
// round-8 algebra re-indexed:
//   out = a^T G a + hb,  a = (c0c1, c0s1, s0c1, s0s1),  G real sym 4x4 from
//   the 4 columns C = U[:, {0,1024,2048,3072}] (batch-invariant).
// Flat y (12b) = [thread T (9b) | reg r (3b)], wire w <-> flat bit 11-w:
//   wires 0..2  -> thread bits 8..6 (wave-crossing) -> LDS exchange gate
//   wires 3..8  -> thread bits 5..0 (lane bits)     -> ds_bpermute gate
//   wires 9..11 -> reg bits 2..0                    -> in-register gate
// Deferred CNOT: physical thread t holds logical p; partner for logical bit
// pb at t ^ Minv[pb] (pi is GF(2)-linear).  d^(d>>1) on (T<<3)|r =
// (G9(T)<<3) | (gray3(r) ^ 4*(T&1)):
//   thread part deferred:  p = ginv9(p); Minv[pb] ^= Minv[pb-1]
//   reg part physical:     cond swap r^4 on c=parity(p_old), gray3 cycles
// Minv[pb] stays a XOR-subset of {1..2^pb} (update only mixes lower masks
// up), so pb<=5 partners are always same-wave (bpermute ok), pb>=6 < 512.
// Rot(phi,th,om) = [[(A,-B),(-C,-D)],[(C,-D),(A,B)]], A=ca*ch B=sa*ch
// C=cb*sh D=sb*sh.
// ---------------------------------------------------------------------------

struct Gate32 { float a, b, c, d; };

__device__ __forceinline__ float bpermf(int addr4, float v) {
    return __int_as_float(__builtin_amdgcn_ds_bpermute(addr4, __float_as_int(v)));
}
__device__ __forceinline__ int ginv9(int y) {          // inverse 9-bit gray
    y ^= y >> 1; y ^= y >> 2; y ^= y >> 4; y ^= y >> 8;
    return y & 511;
}

#define CYC2(A,r0,r1) { float t_=A[r0]; A[r0]=A[r1]; A[r1]=t_; }
#define CYC4(A,r0,r1,r2,r3) { float t_=A[r0]; A[r0]=A[r1]; A[r1]=A[r2]; A[r2]=A[r3]; A[r3]=t_; }

// Gate on reg bit BIT (0..2): pair (r0, r1=r0|1<<BIT) in-register.
template<int BIT>
__device__ __forceinline__ void regg(float ar[8], float ai[8], const Gate32 R) {
#pragma unroll
    for (int r0 = 0; r0 < 8; ++r0) {
        if (r0 & (1 << BIT)) continue;              // compile-time filtered
        const int r1 = r0 | (1 << BIT);
        const float x0r = ar[r0], x0i = ai[r0], x1r = ar[r1], x1i = ai[r1];
        ar[r0] = R.a*x0r + R.b*x0i - R.c*x1r + R.d*x1i;
        ai[r0] = R.a*x0i - R.b*x0r - R.c*x1i - R.d*x1r;
        ar[r1] = R.c*x0r + R.d*x0i + R.a*x1r - R.b*x1i;
        ai[r1] = R.c*x0i - R.d*x0r + R.a*x1i + R.b*x1r;
    }
}

// ---- kernel 1: 4 blocks x 512 threads, one column sim per block -----------
__global__ __launch_bounds__(512, 1)
void sim_kernel(const float* __restrict__ wts, float2* __restrict__ cols) {
    const int t = threadIdx.x;                      // physical thread (9 bits)
    const int b = blockIdx.x;                       // column 0..3

    __shared__ Gate32 gt[96];                       // 1536 B
    __shared__ float2 xb[512 * 9];                  // 36,864 B exchange buffer
                                                    // (stride 9 -> ~4 dw/bank)
    if (t < 96) {                                   // fused coeff table
        const int l = t / 12, w = t % 12;
        const float* lw = wts + l*36 + w*3;
        const float phi = lw[0], th = lw[1], om = lw[2];
        float ch, sh, ca, sa, cb, sb;
        __sincosf(0.5f*th,       &sh, &ch);
        __sincosf(0.5f*(phi+om), &sa, &ca);
        __sincosf(0.5f*(phi-om), &sb, &cb);
        Gate32 r; r.a = ca*ch; r.b = sa*ch; r.c = cb*sh; r.d = sb*sh;
        gt[t] = r;
    }

    float ar[8], ai[8];
#pragma unroll
    for (int j = 0; j < 8; ++j) { ar[j] = 0.f; ai[j] = 0.f; }
    // basis flat index b<<10 -> T = b<<7, r = 0; pi = id initially
    if (t == (b << 7)) ar[0] = 1.f;

    int p = t;                                      // logical thread index
    int Minv[9] = {1, 2, 4, 8, 16, 32, 64, 128, 256};

    __syncthreads();      // *** ROUND-10 FIX: gt[] visible before any read ***

#pragma unroll 1
    for (int l = 0; l < 8; ++l) {
        const int base = l * 12;
        // ---- wires 0..2: logical thread bits 8..6, cross-wave via LDS ----
#pragma unroll
        for (int w = 0; w < 3; ++w) {
            const Gate32 R = gt[base + w];
            const int pb = 8 - w;
            const bool bs = (p >> pb) & 1;
            const float csi = bs ? R.b : -R.b;
            const float cor = bs ? R.c : -R.c;
            __syncthreads();                        // prior xb reads done
            {
                float2* own = xb + t * 9;
#pragma unroll
                for (int j = 0; j < 8; ++j) own[j] = make_float2(ar[j], ai[j]);
            }
            __syncthreads();                        // writes visible
            const float2* par = xb + (t ^ Minv[pb]) * 9;
            float2 pv[8];
#pragma unroll
            for (int j = 0; j < 8; ++j) pv[j] = par[j];
#pragma unroll
            for (int j = 0; j < 8; ++j) {
                const float xr = ar[j], xi = ai[j];
                ar[j] = R.a*xr - csi*xi + cor*pv[j].x + R.d*pv[j].y;
                ai[j] = R.a*xi + csi*xr + cor*pv[j].y - R.d*pv[j].x;
            }
        }
        // ---- wires 3..8: logical thread bits 5..0, same-wave bpermute ----
#pragma unroll
        for (int w = 3; w < 9; ++w) {
            const Gate32 R = gt[base + w];
            const int pb = 8 - w;                   // 5..0
            const bool bs = (p >> pb) & 1;
            const float csi = bs ? R.b : -R.b;
            const float cor = bs ? R.c : -R.c;
            const int addr4 = ((t & 63) ^ Minv[pb]) << 2;   // Minv[pb] < 64
            float tr[8], ti[8];
#pragma unroll
            for (int j = 0; j < 8; ++j) {
                tr[j] = bpermf(addr4, ar[j]);
                ti[j] = bpermf(addr4, ai[j]);
            }
#pragma unroll
            for (int j = 0; j < 8; ++j) {
                const float xr = ar[j], xi = ai[j];
                ar[j] = R.a*xr - csi*xi + cor*tr[j] + R.d*ti[j];
                ai[j] = R.a*xi + csi*xr + cor*ti[j] - R.d*tr[j];
            }
        }
        // ---- wires 9..11: reg bits 2..0, in-register ----
        { const Gate32 R = gt[base +  9]; regg<2>(ar, ai, R); }
        { const Gate32 R = gt[base + 10]; regg<1>(ar, ai, R); }
        { const Gate32 R = gt[base + 11]; regg<0>(ar, ai, R); }
        // ---- CNOT chain: reg part physical, thread part deferred ----
        const int c = __popc(p) & 1;                // bit0 of ginv9(p)
#pragma unroll
        for (int k = 0; k < 4; ++k) {               // old'[x] = old[x ^ 4c]
            float u = ar[k];
            ar[k]   = c ? ar[k+4] : ar[k];
            ar[k+4] = c ? u       : ar[k+4];
            u = ai[k];
            ai[k]   = c ? ai[k+4] : ai[k];
            ai[k+4] = c ? u       : ai[k+4];
        }
        CYC2(ar, 2, 3); CYC4(ar, 4, 6, 5, 7);       // new[r] = old'[gray3(r)]
        CYC2(ai, 2, 3); CYC4(ai, 4, 6, 5, 7);
        p = ginv9(p);
#pragma unroll
        for (int pb = 8; pb >= 1; --pb) Minv[pb] ^= Minv[pb-1];
    }

    // ---- write column in LOGICAL order: y = (p<<3) | j ----
    float4* dst4 = reinterpret_cast<float4*>(cols + b*4096 + (p << 3));
#pragma unroll
    for (int k = 0; k < 4; ++k)
        dst4[k] = make_float4(ar[2*k], ai[2*k], ar[2*k+1], ai[2*k+1]);
}

// ---- kernel 2: redundant G-reduce per block + per-sample quadratic form ---
__global__ __launch_bounds__(256)
void finish_kernel(const float* __restrict__ sb,
                   const float2* __restrict__ cols,
                   const float* __restrict__ hw,
                   const float* __restrict__ hb,
                   float* __restrict__ out, int B) {
    const int tid  = threadIdx.x;
    const int lane = tid & 63, wid = tid >> 6;

    float hwv[12];
#pragma unroll
    for (int w = 0; w < 12; ++w) hwv[w] = hw[w];

    // K(q) splits: q = (it<<8) | tid -> Klo over wires 4..11 (bits 7..0)
    float Klo = 0.f;
#pragma unroll
    for (int w = 4; w < 12; ++w)
        Klo += ((tid >> (11 - w)) & 1) ? -hwv[w] : hwv[w];

    float g[10];
#pragma unroll
    for (int m = 0; m < 10; ++m) g[m] = 0.f;

#pragma unroll 1
    for (int it = 0; it < 16; ++it) {
        const int q = (it << 8) | tid;
        const float2 c0 = cols[q];
        const float2 c1 = cols[4096  + q];
        const float2 c2 = cols[8192  + q];
        const float2 c3 = cols[12288 + q];
        float K = Klo;
#pragma unroll
        for (int w = 0; w < 4; ++w)                 // wires 0..3: bits 11..8
            K += ((it >> (3 - w)) & 1) ? -hwv[w] : hwv[w];
        g[0] += K * (c0.x*c0.x + c0.y*c0.y);
        g[1] += K * (c1.x*c1.x + c1.y*c1.y);
        g[2] += K * (c2.x*c2.x + c2.y*c2.y);
        g[3] += K * (c3.x*c3.x + c3.y*c3.y);
        g[4] += K * (c0.x*c1.x + c0.y*c1.y);
        g[5] += K * (c2.x*c3.x + c2.y*c3.y);
        g[6] += K * (c0.x*c2.y - c0.y*c2.x);
        g[7] += K * (c0.x*c3.y - c0.y*c3.x);
        g[8] += K * (c1.x*c2.y - c1.y*c2.x);
        g[9] += K * (c1.x*c3.y - c1.y*c3.x);
    }

    // block reduce: wave butterfly then cross-wave via LDS
    __shared__ float gsh[4][10];
#pragma unroll
    for (int m = 0; m < 10; ++m) {
#pragma unroll
        for (int off = 1; off < 64; off <<= 1)
            g[m] += bpermf((lane ^ off) << 2, g[m]);
    }
    if (lane == 0) {
#pragma unroll
        for (int m = 0; m < 10; ++m) gsh[wid][m] = g[m];
    }
    __syncthreads();
    float G[10];
#pragma unroll
    for (int m = 0; m < 10; ++m) {
        const float s = gsh[0][m] + gsh[1][m] + gsh[2][m] + gsh[3][m];
        G[m] = (m < 4) ? s : 2.f * s;               // fold 2*Re / 2*Im factor
    }

    const int i = blockIdx.x * 256 + tid;
    if (i < B) {
        const float2 x = *reinterpret_cast<const float2*>(sb + i*8);
        float c0, s0, c1, s1;
        __sincosf(0.5f * x.x, &s0, &c0);
        __sincosf(0.5f * x.y, &s1, &c1);
        const float a0 = c0*c1, a1 = c0*s1, a2 = s0*c1, a3 = s0*s1;
        const float r = G[0]*a0*a0 + G[1]*a1*a1 + G[2]*a2*a2 + G[3]*a3*a3
                      + G[4]*(a0*a1) + G[5]*(a2*a3)
                      + G[6]*(a0*a2) + G[7]*(a0*a3)
                      + G[8]*(a1*a2) + G[9]*(a1*a3);
        out[i] = r + hb[0];
    }
}

extern "C" void kernel_launch(void* const* d_in, const int* in_sizes, int n_in,
                              void* d_out, int out_size, void* d_ws, size_t ws_size,
                              hipStream_t stream) {
    const float* sb  = (const float*)d_in[0];
    const float* wts = (const float*)d_in[1];
    const float* hw  = (const float*)d_in[2];
    const float* hb  = (const float*)d_in[3];
    float* out = (float*)d_out;
    float2* cols = (float2*)d_ws;                 // 4 * 4096 * 8 B = 128 KB
    const int B = in_sizes[0] / 8;                // (B,8) state_batch
    sim_kernel   <<<4, 512, 0, stream>>>(wts, cols);
    finish_kernel<<<(B + 255)/256, 256, 0, stream>>>(sb, cols, hw, hb, out, B);
}

// Round 4
// 105.394 us; speedup vs baseline: 4.5680x; 1.0605x over previous
//
#include <hip/hip_runtime.h>
#include <hip/hip_fp16.h>

// ---------------------------------------------------------------------------
// ROUND 11: halve sim_kernel's LDS traffic + barriers. Round 10 measured
// sim = 47.9 us, LDS-issue-bound (96 bpermute + 48 b64 + 6 barriers per
// thread-layer across 8 waves sharing one LDS pipe) with ~30k cycles of
// barrier tax (48 full-drain __syncthreads).
// Key algebra: a 1-wire gate's partner contribution is TWO reals:
//   P = cor_r*tr + D*ti,  Q = cor_r*ti - D*tr,  and cor_sender = -cor_recv
// so the SENDER pre-combines u = cor_s*ar - D*ai, v = cor_s*ai + D*ar and
// the receiver uses (P,Q) = (-u,-v): ONE half2 per complex amplitude.
//   - lane-wire gates: 8 bpermutes/gate (was 16)
//   - exchange gates:  4 ds_write_b64 + 4 ds_read_b64 /gate (was 8+8 b64)
//   - fp16 transfer precision OK: round 7 ran the WHOLE state in fp16 at
//     absmax 9.8e-4 (threshold 3.45e-3); here only partner terms rounded.
// Exchange buffer shrinks to 512x10 half2 = 20 KB -> DOUBLE-BUFFERED within
// the 64 KB static-LDS limit -> 1 barrier per exchange gate (24 total,
// was 48). WAR safety: gate g+2 reuses buf (g&1), and gate g+1's barrier
// sits between g's reads (consumed pre-barrier) and g+2's writes.
// Everything else is the verified round-10 structure:
//   out = a^T G a + hb, a = (c0c1,c0s1,s0c1,s0s1); G from 4 columns of U.
//   flat y = [thread T(9b) | reg r(3b)]; wire w <-> flat bit 11-w;
//   wires 0..2 -> LDS exchange, 3..8 -> bpermute, 9..11 -> in-register.
//   CNOT chain deferred on thread bits (p, Minv), physical on reg bits
//   (cond swap r^4 on parity(p_old) + gray3 cycles).
// Rot(phi,th,om) = [[(A,-B),(-C,-D)],[(C,-D),(A,B)]], A=ca*ch B=sa*ch
// C=cb*sh D=sb*sh.
// ---------------------------------------------------------------------------

struct Gate32 { float a, b, c, d; };

__device__ __forceinline__ float bpermf(int addr4, float v) {
    return __int_as_float(__builtin_amdgcn_ds_bpermute(addr4, __float_as_int(v)));
}
__device__ __forceinline__ __half2 bperm2(int addr4, __half2 v) {
    int x = __builtin_amdgcn_ds_bpermute(addr4, __builtin_bit_cast(int, v));
    return __builtin_bit_cast(__half2, x);
}
__device__ __forceinline__ int ginv9(int y) {          // inverse 9-bit gray
    y ^= y >> 1; y ^= y >> 2; y ^= y >> 4; y ^= y >> 8;
    return y & 511;
}

#define CYC2(A,r0,r1) { float t_=A[r0]; A[r0]=A[r1]; A[r1]=t_; }
#define CYC4(A,r0,r1,r2,r3) { float t_=A[r0]; A[r0]=A[r1]; A[r1]=A[r2]; A[r2]=A[r3]; A[r3]=t_; }

// Gate on reg bit BIT (0..2): pair (r0, r1=r0|1<<BIT) in-register.
template<int BIT>
__device__ __forceinline__ void regg(float ar[8], float ai[8], const Gate32 R) {
#pragma unroll
    for (int r0 = 0; r0 < 8; ++r0) {
        if (r0 & (1 << BIT)) continue;              // compile-time filtered
        const int r1 = r0 | (1 << BIT);
        const float x0r = ar[r0], x0i = ai[r0], x1r = ar[r1], x1i = ai[r1];
        ar[r0] = R.a*x0r + R.b*x0i - R.c*x1r + R.d*x1i;
        ai[r0] = R.a*x0i - R.b*x0r - R.c*x1i - R.d*x1r;
        ar[r1] = R.c*x0r + R.d*x0i + R.a*x1r - R.b*x1i;
        ai[r1] = R.c*x0i - R.d*x0r + R.a*x1i + R.b*x1r;
    }
}

// ---- kernel 1: 4 blocks x 512 threads, one column sim per block -----------
__global__ __launch_bounds__(512, 1)
void sim_kernel(const float* __restrict__ wts, float2* __restrict__ cols) {
    const int t = threadIdx.x;                      // physical thread (9 bits)
    const int b = blockIdx.x;                       // column 0..3

    __shared__ Gate32 gt[96];                       // 1,536 B
    __shared__ __half2 xb[2][512 * 10];             // 2 x 20,480 B dbuf
                                                    // (stride 10 h2 = 40 B:
                                                    //  8B-aligned, ~4-way bk)
    if (t < 96) {                                   // fused coeff table
        const int l = t / 12, w = t % 12;
        const float* lw = wts + l*36 + w*3;
        const float phi = lw[0], th = lw[1], om = lw[2];
        float ch, sh, ca, sa, cb, sb;
        __sincosf(0.5f*th,       &sh, &ch);
        __sincosf(0.5f*(phi+om), &sa, &ca);
        __sincosf(0.5f*(phi-om), &sb, &cb);
        Gate32 r; r.a = ca*ch; r.b = sa*ch; r.c = cb*sh; r.d = sb*sh;
        gt[t] = r;
    }

    float ar[8], ai[8];
#pragma unroll
    for (int j = 0; j < 8; ++j) { ar[j] = 0.f; ai[j] = 0.f; }
    // basis flat index b<<10 -> T = b<<7, r = 0; pi = id initially
    if (t == (b << 7)) ar[0] = 1.f;

    int p = t;                                      // logical thread index
    int Minv[9] = {1, 2, 4, 8, 16, 32, 64, 128, 256};

    __syncthreads();                                // gt[] visible (R10 fix)

#pragma unroll 1
    for (int l = 0; l < 8; ++l) {
        const int base = l * 12;
        // ---- wires 0..2: thread bits 8..6, cross-wave via dbuf LDS ----
#pragma unroll
        for (int w = 0; w < 3; ++w) {
            const Gate32 R = gt[base + w];
            const int pb = 8 - w;
            const bool bs = (p >> pb) & 1;
            const float csi = bs ? R.b : -R.b;
            const float cor = bs ? R.c : -R.c;
            __half2* buf = xb[(l*3 + w) & 1];
            // sender-side pre-combine: u = cor*ar - D*ai, v = cor*ai + D*ar
            __half2* own = buf + t * 10;
#pragma unroll
            for (int k = 0; k < 4; ++k) {
                const int j0 = 2*k, j1 = 2*k + 1;
                const __half2 p0 = __floats2half2_rn(cor*ar[j0] - R.d*ai[j0],
                                                     cor*ai[j0] + R.d*ar[j0]);
                const __half2 p1 = __floats2half2_rn(cor*ar[j1] - R.d*ai[j1],
                                                     cor*ai[j1] + R.d*ar[j1]);
                reinterpret_cast<int2*>(own)[k] =
                    make_int2(__builtin_bit_cast(int, p0),
                              __builtin_bit_cast(int, p1));
            }
            __syncthreads();                        // writes visible
            const __half2* par = buf + (t ^ Minv[pb]) * 10;
            int2 q[4];
#pragma unroll
            for (int k = 0; k < 4; ++k)
                q[k] = reinterpret_cast<const int2*>(par)[k];
#pragma unroll
            for (int k = 0; k < 4; ++k) {
                const __half2 u0 = __builtin_bit_cast(__half2, q[k].x);
                const __half2 u1 = __builtin_bit_cast(__half2, q[k].y);
                const int j0 = 2*k, j1 = 2*k + 1;
                float xr = ar[j0], xi = ai[j0];
                ar[j0] = R.a*xr - csi*xi - __low2float(u0);
                ai[j0] = R.a*xi + csi*xr - __high2float(u0);
                xr = ar[j1]; xi = ai[j1];
                ar[j1] = R.a*xr - csi*xi - __low2float(u1);
                ai[j1] = R.a*xi + csi*xr - __high2float(u1);
            }
        }
        // ---- wires 3..8: lane bits 5..0, half2-packed bpermute ----
#pragma unroll
        for (int w = 3; w < 9; ++w) {
            const Gate32 R = gt[base + w];
            const int pb = 8 - w;                   // 5..0
            const bool bs = (p >> pb) & 1;
            const float csi = bs ? R.b : -R.b;
            const float cor = bs ? R.c : -R.c;
            const int addr4 = ((t & 63) ^ Minv[pb]) << 2;   // Minv[pb] < 64
            __half2 pk[8];
#pragma unroll
            for (int j = 0; j < 8; ++j)
                pk[j] = __floats2half2_rn(cor*ar[j] - R.d*ai[j],
                                          cor*ai[j] + R.d*ar[j]);
            __half2 q[8];
#pragma unroll
            for (int j = 0; j < 8; ++j) q[j] = bperm2(addr4, pk[j]);
#pragma unroll
            for (int j = 0; j < 8; ++j) {
                const float xr = ar[j], xi = ai[j];
                ar[j] = R.a*xr - csi*xi - __low2float(q[j]);
                ai[j] = R.a*xi + csi*xr - __high2float(q[j]);
            }
        }
        // ---- wires 9..11: reg bits 2..0, in-register (f32) ----
        { const Gate32 R = gt[base +  9]; regg<2>(ar, ai, R); }
        { const Gate32 R = gt[base + 10]; regg<1>(ar, ai, R); }
        { const Gate32 R = gt[base + 11]; regg<0>(ar, ai, R); }
        // ---- CNOT chain: reg part physical, thread part deferred ----
        const int c = __popc(p) & 1;                // bit0 of ginv9(p)
#pragma unroll
        for (int k = 0; k < 4; ++k) {               // old'[x] = old[x ^ 4c]
            float u = ar[k];
            ar[k]   = c ? ar[k+4] : ar[k];
            ar[k+4] = c ? u       : ar[k+4];
            u = ai[k];
            ai[k]   = c ? ai[k+4] : ai[k];
            ai[k+4] = c ? u       : ai[k+4];
        }
        CYC2(ar, 2, 3); CYC4(ar, 4, 6, 5, 7);       // new[r] = old'[gray3(r)]
        CYC2(ai, 2, 3); CYC4(ai, 4, 6, 5, 7);
        p = ginv9(p);
#pragma unroll
        for (int pb = 8; pb >= 1; --pb) Minv[pb] ^= Minv[pb-1];
    }

    // ---- write column in LOGICAL order: y = (p<<3) | j ----
    float4* dst4 = reinterpret_cast<float4*>(cols + b*4096 + (p << 3));
#pragma unroll
    for (int k = 0; k < 4; ++k)
        dst4[k] = make_float4(ar[2*k], ai[2*k], ar[2*k+1], ai[2*k+1]);
}

// ---- kernel 2: redundant G-reduce per block + per-sample quadratic form ---
__global__ __launch_bounds__(256)
void finish_kernel(const float* __restrict__ sb,
                   const float2* __restrict__ cols,
                   const float* __restrict__ hw,
                   const float* __restrict__ hb,
                   float* __restrict__ out, int B) {
    const int tid  = threadIdx.x;
    const int lane = tid & 63, wid = tid >> 6;

    float hwv[12];
#pragma unroll
    for (int w = 0; w < 12; ++w) hwv[w] = hw[w];

    // K(q) splits: q = (it<<8) | tid -> Klo over wires 4..11 (bits 7..0)
    float Klo = 0.f;
#pragma unroll
    for (int w = 4; w < 12; ++w)
        Klo += ((tid >> (11 - w)) & 1) ? -hwv[w] : hwv[w];

    float g[10];
#pragma unroll
    for (int m = 0; m < 10; ++m) g[m] = 0.f;

#pragma unroll 1
    for (int it = 0; it < 16; ++it) {
        const int q = (it << 8) | tid;
        const float2 c0 = cols[q];
        const float2 c1 = cols[4096  + q];
        const float2 c2 = cols[8192  + q];
        const float2 c3 = cols[12288 + q];
        float K = Klo;
#pragma unroll
        for (int w = 0; w < 4; ++w)                 // wires 0..3: bits 11..8
            K += ((it >> (3 - w)) & 1) ? -hwv[w] : hwv[w];
        g[0] += K * (c0.x*c0.x + c0.y*c0.y);
        g[1] += K * (c1.x*c1.x + c1.y*c1.y);
        g[2] += K * (c2.x*c2.x + c2.y*c2.y);
        g[3] += K * (c3.x*c3.x + c3.y*c3.y);
        g[4] += K * (c0.x*c1.x + c0.y*c1.y);
        g[5] += K * (c2.x*c3.x + c2.y*c3.y);
        g[6] += K * (c0.x*c2.y - c0.y*c2.x);
        g[7] += K * (c0.x*c3.y - c0.y*c3.x);
        g[8] += K * (c1.x*c2.y - c1.y*c2.x);
        g[9] += K * (c1.x*c3.y - c1.y*c3.x);
    }

    // block reduce: wave butterfly then cross-wave via LDS
    __shared__ float gsh[4][10];
#pragma unroll
    for (int m = 0; m < 10; ++m) {
#pragma unroll
        for (int off = 1; off < 64; off <<= 1)
            g[m] += bpermf((lane ^ off) << 2, g[m]);
    }
    if (lane == 0) {
#pragma unroll
        for (int m = 0; m < 10; ++m) gsh[wid][m] = g[m];
    }
    __syncthreads();
    float G[10];
#pragma unroll
    for (int m = 0; m < 10; ++m) {
        const float s = gsh[0][m] + gsh[1][m] + gsh[2][m] + gsh[3][m];
        G[m] = (m < 4) ? s : 2.f * s;               // fold 2*Re / 2*Im factor
    }

    const int i = blockIdx.x * 256 + tid;
    if (i < B) {
        const float2 x = *reinterpret_cast<const float2*>(sb + i*8);
        float c0, s0, c1, s1;
        __sincosf(0.5f * x.x, &s0, &c0);
        __sincosf(0.5f * x.y, &s1, &c1);
        const float a0 = c0*c1, a1 = c0*s1, a2 = s0*c1, a3 = s0*s1;
        const float r = G[0]*a0*a0 + G[1]*a1*a1 + G[2]*a2*a2 + G[3]*a3*a3
                      + G[4]*(a0*a1) + G[5]*(a2*a3)
                      + G[6]*(a0*a2) + G[7]*(a0*a3)
                      + G[8]*(a1*a2) + G[9]*(a1*a3);
        out[i] = r + hb[0];
    }
}

extern "C" void kernel_launch(void* const* d_in, const int* in_sizes, int n_in,
                              void* d_out, int out_size, void* d_ws, size_t ws_size,
                              hipStream_t stream) {
    const float* sb  = (const float*)d_in[0];
    const float* wts = (const float*)d_in[1];
    const float* hw  = (const float*)d_in[2];
    const float* hb  = (const float*)d_in[3];
    float* out = (float*)d_out;
    float2* cols = (float2*)d_ws;                 // 4 * 4096 * 8 B = 128 KB
    const int B = in_sizes[0] / 8;                // (B,8) state_batch
    sim_kernel   <<<4, 512, 0, stream>>>(wts, cols);
    finish_kernel<<<(B + 255)/256, 256, 0, stream>>>(sb, cols, hw, hb, out, B);
}

// Round 5
// 92.212 us; speedup vs baseline: 5.2210x; 1.1429x over previous
//
#include <hip/hip_runtime.h>
#include <hip/hip_fp16.h>

// ---------------------------------------------------------------------------
// ROUND 12: fp16-packed state + v_pk_fma_f16 everywhere. Round 11 counters:
// sim = 42 us, VALUBusy ~64% of the 4 active CUs (~64k VALU cycles of 100k
// total) -> VALU-bound, dominated by f32<->f16 cvt/pack on every comm gate
// and scalar-f32 gate FMAs. This round grafts round 7's HW-verified fp16
// packing (element r = 2k+h in half h of ar2[k]/ai2[k]; all gate math in
// packed half2 ops) onto the verified round-10/11 distributed structure:
//   - comm paths lose ALL cvts (state already half2; u,v = 2 pk-ops each)
//   - every gate's FMA count halves (2-wide packed)
//   - state = 8 VGPRs (4 ar2 + 4 ai2)
// DS unchanged (72 ops/thread-layer = 1 dword/complex, info-theoretic min),
// barriers unchanged (24). Precision: R7 ran the whole 96-gate circuit fp16
// at absmax 9.77e-4 (threshold 3.45e-3) -- same depth here.
// Structure (verified R10/R11): out = a^T G a + hb, a=(c0c1,c0s1,s0c1,s0s1);
// G real sym 4x4 from columns C = U[:,{0,1024,2048,3072}].
// Flat y = [thread T(9b) | reg r(3b)]; wire w <-> flat bit 11-w:
//   wires 0..2 -> thread bits 8..6: LDS exchange (dbuf, 1 barrier/gate)
//   wires 3..8 -> thread bits 5..0: ds_bpermute
//   wires 9..11 -> reg bits 2..0:  in-register packed (R7 forms)
// Deferred CNOT: p = ginv9(p); Minv[pb] ^= Minv[pb-1]; physical reg part =
// cond swap r^4 on c=parity(p_old) (h2 pairs 0<->2,1<->3) + gray3 relabel
// {h1<-swap(h1), h2<-h3, h3<-swap(h2)}, swap = 16-bit rotate.
// Sender pre-combine (R11-verified signs): u = cor*xr - D*xi, v = cor*xi
// + D*xr with cor = bs?C:-C, csi = bs?B:-B; receiver: re' = A*xr - csi*xi
// - u_fetched; im' = A*xi + csi*xr - v_fetched.
// Rot(phi,th,om) = [[(A,-B),(-C,-D)],[(C,-D),(A,B)]], A=ca*ch B=sa*ch
// C=cb*sh D=sb*sh.
// ---------------------------------------------------------------------------

typedef __half2 h2;
struct Gate32 { float a, b, c, d; };

__device__ __forceinline__ float bpermf(int addr4, float v) {
    return __int_as_float(__builtin_amdgcn_ds_bpermute(addr4, __float_as_int(v)));
}
__device__ __forceinline__ h2 bperm2(int addr4, h2 v) {
    int x = __builtin_amdgcn_ds_bpermute(addr4, __builtin_bit_cast(int, v));
    return __builtin_bit_cast(h2, x);
}
__device__ __forceinline__ int ginv9(int y) {          // inverse 9-bit gray
    y ^= y >> 1; y ^= y >> 2; y ^= y >> 4; y ^= y >> 8;
    return y & 511;
}
__device__ __forceinline__ h2 sp(float x) {            // splat f32 -> half2
    return __half2half2(__float2half(x));
}
__device__ __forceinline__ h2 rot16(h2 v) {            // swap the two halves
    unsigned u = __builtin_bit_cast(unsigned, v);
    u = (u << 16) | (u >> 16);
    return __builtin_bit_cast(h2, u);
}

// R7-verified packed 2x2 gate on an aligned half2 pair.
struct H2C { h2 a, b, c, d, nb, nc, nd; };
__device__ __forceinline__ void reg_pair(h2& a0r, h2& a0i, h2& a1r, h2& a1i,
                                         const H2C& R) {
    const h2 x0r = a0r, x0i = a0i, x1r = a1r, x1i = a1i;
    a0r = __hfma2(R.d,  x1i, __hfma2(R.nc, x1r, __hfma2(R.b,  x0i, __hmul2(R.a, x0r))));
    a0i = __hfma2(R.nd, x1r, __hfma2(R.nc, x1i, __hfma2(R.nb, x0r, __hmul2(R.a, x0i))));
    a1r = __hfma2(R.nb, x1i, __hfma2(R.a,  x1r, __hfma2(R.d,  x0i, __hmul2(R.c, x0r))));
    a1i = __hfma2(R.b,  x1r, __hfma2(R.a,  x1i, __hfma2(R.nd, x0r, __hmul2(R.c, x0i))));
}

// ---- kernel 1: 4 blocks x 512 threads, one column sim per block -----------
__global__ __launch_bounds__(512, 1)
void sim_kernel(const float* __restrict__ wts, float2* __restrict__ cols) {
    const int t = threadIdx.x;                      // physical thread (9 bits)
    const int b = blockIdx.x;                       // column 0..3

    __shared__ Gate32 gt[96];                       // 1,536 B
    __shared__ h2 xb[2][512 * 10];                  // 2 x 20,480 B dbuf
                                                    // (R11 layout: 0 conflicts)
    if (t < 96) {                                   // fused coeff table
        const int l = t / 12, w = t % 12;
        const float* lw = wts + l*36 + w*3;
        const float phi = lw[0], th = lw[1], om = lw[2];
        float ch, sh, ca, sa, cb, sb;
        __sincosf(0.5f*th,       &sh, &ch);
        __sincosf(0.5f*(phi+om), &sa, &ca);
        __sincosf(0.5f*(phi-om), &sb, &cb);
        Gate32 r; r.a = ca*ch; r.b = sa*ch; r.c = cb*sh; r.d = sb*sh;
        gt[t] = r;
    }

    h2 ar2[4], ai2[4];
    const h2 zero = sp(0.f);
#pragma unroll
    for (int k = 0; k < 4; ++k) { ar2[k] = zero; ai2[k] = zero; }
    // basis flat index b<<10 -> T = b<<7, r = 0
    if (t == (b << 7)) ar2[0] = __halves2half2(__float2half(1.f), __float2half(0.f));

    int p = t;                                      // logical thread index
    int Minv[9] = {1, 2, 4, 8, 16, 32, 64, 128, 256};

    __syncthreads();                                // gt[] visible (R10 fix)

#pragma unroll 1
    for (int l = 0; l < 8; ++l) {
        const int base = l * 12;
        // ---- wires 0..2: thread bits 8..6, cross-wave via dbuf LDS ----
#pragma unroll
        for (int w = 0; w < 3; ++w) {
            const Gate32 R = gt[base + w];
            const int pb = 8 - w;
            const bool bs = (p >> pb) & 1;
            const h2 A2   = sp(R.a);
            const h2 csi2 = sp(bs ? R.b : -R.b);
            const h2 ncsi2 = __hneg2(csi2);
            const h2 cor2 = sp(bs ? R.c : -R.c);
            const h2 D2   = sp(R.d);
            const h2 nD2  = __hneg2(D2);
            h2* buf = xb[(l*3 + w) & 1];
            h2* own = buf + t * 10;
#pragma unroll
            for (int k = 0; k < 4; ++k) {           // u = cor*xr - D*xi
                const h2 u = __hfma2(nD2, ai2[k], __hmul2(cor2, ar2[k]));
                const h2 v = __hfma2(D2,  ar2[k], __hmul2(cor2, ai2[k]));
                reinterpret_cast<int2*>(own)[k] =
                    make_int2(__builtin_bit_cast(int, u),
                              __builtin_bit_cast(int, v));
            }
            __syncthreads();                        // writes visible
            const h2* par = buf + (t ^ Minv[pb]) * 10;
            int2 q[4];
#pragma unroll
            for (int k = 0; k < 4; ++k)
                q[k] = reinterpret_cast<const int2*>(par)[k];
#pragma unroll
            for (int k = 0; k < 4; ++k) {
                const h2 U = __builtin_bit_cast(h2, q[k].x);
                const h2 V = __builtin_bit_cast(h2, q[k].y);
                const h2 nr = __hsub2(__hfma2(ncsi2, ai2[k], __hmul2(A2, ar2[k])), U);
                const h2 ni = __hsub2(__hfma2(csi2,  ar2[k], __hmul2(A2, ai2[k])), V);
                ar2[k] = nr; ai2[k] = ni;
            }
        }
        // ---- wires 3..8: lane bits 5..0, packed bpermute ----
#pragma unroll
        for (int w = 3; w < 9; ++w) {
            const Gate32 R = gt[base + w];
            const int pb = 8 - w;                   // 5..0
            const bool bs = (p >> pb) & 1;
            const h2 A2   = sp(R.a);
            const h2 csi2 = sp(bs ? R.b : -R.b);
            const h2 ncsi2 = __hneg2(csi2);
            const h2 cor2 = sp(bs ? R.c : -R.c);
            const h2 D2   = sp(R.d);
            const h2 nD2  = __hneg2(D2);
            const int addr4 = ((t & 63) ^ Minv[pb]) << 2;   // Minv[pb] < 64
            h2 u[4], v[4];
#pragma unroll
            for (int k = 0; k < 4; ++k) {
                u[k] = __hfma2(nD2, ai2[k], __hmul2(cor2, ar2[k]));
                v[k] = __hfma2(D2,  ar2[k], __hmul2(cor2, ai2[k]));
            }
            h2 U[4], V[4];
#pragma unroll
            for (int k = 0; k < 4; ++k) {
                U[k] = bperm2(addr4, u[k]);
                V[k] = bperm2(addr4, v[k]);
            }
#pragma unroll
            for (int k = 0; k < 4; ++k) {
                const h2 nr = __hsub2(__hfma2(ncsi2, ai2[k], __hmul2(A2, ar2[k])), U[k]);
                const h2 ni = __hsub2(__hfma2(csi2,  ar2[k], __hmul2(A2, ai2[k])), V[k]);
                ar2[k] = nr; ai2[k] = ni;
            }
        }
        // ---- wires 9..10: reg bits 2..1, aligned-half2 pairs (R7 form) ----
        {
            const Gate32 R = gt[base + 9];          // BIT2: pairs (0,2),(1,3)
            H2C C; C.a = sp(R.a); C.b = sp(R.b); C.c = sp(R.c); C.d = sp(R.d);
            C.nb = __hneg2(C.b); C.nc = __hneg2(C.c); C.nd = __hneg2(C.d);
            reg_pair(ar2[0], ai2[0], ar2[2], ai2[2], C);
            reg_pair(ar2[1], ai2[1], ar2[3], ai2[3], C);
        }
        {
            const Gate32 R = gt[base + 10];         // BIT1: pairs (0,1),(2,3)
            H2C C; C.a = sp(R.a); C.b = sp(R.b); C.c = sp(R.c); C.d = sp(R.d);
            C.nb = __hneg2(C.b); C.nc = __hneg2(C.c); C.nd = __hneg2(C.d);
            reg_pair(ar2[0], ai2[0], ar2[1], ai2[1], C);
            reg_pair(ar2[2], ai2[2], ar2[3], ai2[3], C);
        }
        // ---- wire 11: reg bit 0, intra-half2 (R7 reg_gate_lo constants) ----
        {
            const Gate32 R = gt[base + 11];
            const h2 cP  = __halves2half2(__float2half( R.a), __float2half( R.c));
            const h2 cQ  = __halves2half2(__float2half( R.b), __float2half( R.d));
            const h2 cR  = __halves2half2(__float2half(-R.c), __float2half( R.a));
            const h2 cS  = __halves2half2(__float2half( R.d), __float2half(-R.b));
            const h2 cQn = __hneg2(cQ);
            const h2 cSn = __hneg2(cS);
#pragma unroll
            for (int k = 0; k < 4; ++k) {
                const h2 arv = ar2[k], aiv = ai2[k];
                const h2 arx = __low2half2(arv), ary = __high2half2(arv);
                const h2 aix = __low2half2(aiv), aiy = __high2half2(aiv);
                ar2[k] = __hfma2(cS,  aiy, __hfma2(cR, ary, __hfma2(cQ,  aix, __hmul2(cP, arx))));
                ai2[k] = __hfma2(cSn, ary, __hfma2(cR, aiy, __hfma2(cQn, arx, __hmul2(cP, aix))));
            }
        }
        // ---- CNOT chain: reg part physical (packed), thread part deferred --
        const int c = __popc(p) & 1;                // parity of OLD logical p
        {
            h2 t0;                                  // cond swap r ^ 4
            t0 = ar2[0]; ar2[0] = c ? ar2[2] : ar2[0]; ar2[2] = c ? t0 : ar2[2];
            t0 = ar2[1]; ar2[1] = c ? ar2[3] : ar2[1]; ar2[3] = c ? t0 : ar2[3];
            t0 = ai2[0]; ai2[0] = c ? ai2[2] : ai2[0]; ai2[2] = c ? t0 : ai2[2];
            t0 = ai2[1]; ai2[1] = c ? ai2[3] : ai2[1]; ai2[3] = c ? t0 : ai2[3];
            // gray3 relabel: h1 <- swap(h1); h2 <- h3; h3 <- swap(h2_old)
            h2 tmp = ar2[2]; ar2[2] = ar2[3]; ar2[3] = rot16(tmp);
            ar2[1] = rot16(ar2[1]);
            tmp = ai2[2]; ai2[2] = ai2[3]; ai2[3] = rot16(tmp);
            ai2[1] = rot16(ai2[1]);
        }
        p = ginv9(p);
#pragma unroll
        for (int pb = 8; pb >= 1; --pb) Minv[pb] ^= Minv[pb-1];
    }

    // ---- write column in LOGICAL order: y = (p<<3) | j ----
    float4* dst4 = reinterpret_cast<float4*>(cols + b*4096 + (p << 3));
#pragma unroll
    for (int k = 0; k < 4; ++k)
        dst4[k] = make_float4(__low2float(ar2[k]),  __low2float(ai2[k]),
                              __high2float(ar2[k]), __high2float(ai2[k]));
}

// ---- kernel 2: redundant G-reduce per block + per-sample quadratic form ---
__global__ __launch_bounds__(256)
void finish_kernel(const float* __restrict__ sb,
                   const float2* __restrict__ cols,
                   const float* __restrict__ hw,
                   const float* __restrict__ hb,
                   float* __restrict__ out, int B) {
    const int tid  = threadIdx.x;
    const int lane = tid & 63, wid = tid >> 6;

    float hwv[12];
#pragma unroll
    for (int w = 0; w < 12; ++w) hwv[w] = hw[w];

    // K(q) splits: q = (it<<8) | tid -> Klo over wires 4..11 (bits 7..0)
    float Klo = 0.f;
#pragma unroll
    for (int w = 4; w < 12; ++w)
        Klo += ((tid >> (11 - w)) & 1) ? -hwv[w] : hwv[w];

    float g[10];
#pragma unroll
    for (int m = 0; m < 10; ++m) g[m] = 0.f;

#pragma unroll 1
    for (int it = 0; it < 16; ++it) {
        const int q = (it << 8) | tid;
        const float2 c0 = cols[q];
        const float2 c1 = cols[4096  + q];
        const float2 c2 = cols[8192  + q];
        const float2 c3 = cols[12288 + q];
        float K = Klo;
#pragma unroll
        for (int w = 0; w < 4; ++w)                 // wires 0..3: bits 11..8
            K += ((it >> (3 - w)) & 1) ? -hwv[w] : hwv[w];
        g[0] += K * (c0.x*c0.x + c0.y*c0.y);
        g[1] += K * (c1.x*c1.x + c1.y*c1.y);
        g[2] += K * (c2.x*c2.x + c2.y*c2.y);
        g[3] += K * (c3.x*c3.x + c3.y*c3.y);
        g[4] += K * (c0.x*c1.x + c0.y*c1.y);
        g[5] += K * (c2.x*c3.x + c2.y*c3.y);
        g[6] += K * (c0.x*c2.y - c0.y*c2.x);
        g[7] += K * (c0.x*c3.y - c0.y*c3.x);
        g[8] += K * (c1.x*c2.y - c1.y*c2.x);
        g[9] += K * (c1.x*c3.y - c1.y*c3.x);
    }

    // block reduce: wave butterfly then cross-wave via LDS
    __shared__ float gsh[4][10];
#pragma unroll
    for (int m = 0; m < 10; ++m) {
#pragma unroll
        for (int off = 1; off < 64; off <<= 1)
            g[m] += bpermf((lane ^ off) << 2, g[m]);
    }
    if (lane == 0) {
#pragma unroll
        for (int m = 0; m < 10; ++m) gsh[wid][m] = g[m];
    }
    __syncthreads();
    float G[10];
#pragma unroll
    for (int m = 0; m < 10; ++m) {
        const float s = gsh[0][m] + gsh[1][m] + gsh[2][m] + gsh[3][m];
        G[m] = (m < 4) ? s : 2.f * s;               // fold 2*Re / 2*Im factor
    }

    const int i = blockIdx.x * 256 + tid;
    if (i < B) {
        const float2 x = *reinterpret_cast<const float2*>(sb + i*8);
        float c0, s0, c1, s1;
        __sincosf(0.5f * x.x, &s0, &c0);
        __sincosf(0.5f * x.y, &s1, &c1);
        const float a0 = c0*c1, a1 = c0*s1, a2 = s0*c1, a3 = s0*s1;
        const float r = G[0]*a0*a0 + G[1]*a1*a1 + G[2]*a2*a2 + G[3]*a3*a3
                      + G[4]*(a0*a1) + G[5]*(a2*a3)
                      + G[6]*(a0*a2) + G[7]*(a0*a3)
                      + G[8]*(a1*a2) + G[9]*(a1*a3);
        out[i] = r + hb[0];
    }
}

extern "C" void kernel_launch(void* const* d_in, const int* in_sizes, int n_in,
                              void* d_out, int out_size, void* d_ws, size_t ws_size,
                              hipStream_t stream) {
    const float* sb  = (const float*)d_in[0];
    const float* wts = (const float*)d_in[1];
    const float* hw  = (const float*)d_in[2];
    const float* hb  = (const float*)d_in[3];
    float* out = (float*)d_out;
    float2* cols = (float2*)d_ws;                 // 4 * 4096 * 8 B = 128 KB
    const int B = in_sizes[0] / 8;                // (B,8) state_batch
    sim_kernel   <<<4, 512, 0, stream>>>(wts, cols);
    finish_kernel<<<(B + 255)/256, 256, 0, stream>>>(sb, cols, hw, hb, out, B);
}